// Round 2
// baseline (836.596 us; speedup 1.0000x reference)
//
#include <hip/hip_runtime.h>
#include <hip/hip_bf16.h>
#include <cstdint>
#include <cstddef>

// Problem constants
#define BB   8192
#define DIN  1024
#define DD   768
#define CC   16384

typedef __bf16 bf16x8 __attribute__((ext_vector_type(8)));
typedef __bf16 bf16x4 __attribute__((ext_vector_type(4)));
typedef float  floatx4 __attribute__((ext_vector_type(4)));

__device__ __forceinline__ void gload_lds16(const void* g, void* l) {
    __builtin_amdgcn_global_load_lds(
        (const __attribute__((address_space(1))) void*)g,
        (__attribute__((address_space(3))) void*)l,
        16, 0, 0);
}

// ---------------- prep kernels ----------------

// fp32 -> bf16, 4 elements/thread (exact grid)
__global__ __launch_bounds__(256) void f2b_kernel(const float4* __restrict__ in,
                                                  bf16x4* __restrict__ out) {
    size_t i = (size_t)blockIdx.x * 256 + threadIdx.x;
    float4 v = in[i];
    bf16x4 o;
    o.x = (__bf16)v.x; o.y = (__bf16)v.y; o.z = (__bf16)v.z; o.w = (__bf16)v.w;
    out[i] = o;
}

// per-row: convert fp32 row -> bf16 row, and sumsq of the *rounded* values -> sq[row]
__global__ __launch_bounds__(256) void row_convert_sumsq_f32(const float* __restrict__ src,
                                                             __bf16* __restrict__ dst,
                                                             float* __restrict__ sq,
                                                             int Dd) {
    int row = blockIdx.x;
    int tid = threadIdx.x, lane = tid & 63, wave = tid >> 6;
    const float* s = src + (size_t)row * Dd;
    __bf16* d = dst + (size_t)row * Dd;
    float acc = 0.f;
    for (int j = tid; j < Dd; j += 256) {
        __bf16 b = (__bf16)s[j];
        d[j] = b;
        float f = (float)b;
        acc += f * f;
    }
    for (int off = 32; off > 0; off >>= 1) acc += __shfl_xor(acc, off, 64);
    __shared__ float red[4];
    if (lane == 0) red[wave] = acc;
    __syncthreads();
    if (tid == 0) sq[row] = red[0] + red[1] + red[2] + red[3];
}

// per-row sumsq of a bf16 matrix
__global__ __launch_bounds__(256) void row_sumsq_bf16(const __bf16* __restrict__ src,
                                                      float* __restrict__ sq,
                                                      int Dd) {
    int row = blockIdx.x;
    int tid = threadIdx.x, lane = tid & 63, wave = tid >> 6;
    const __bf16* s = src + (size_t)row * Dd;
    float acc = 0.f;
    for (int j = tid; j < Dd; j += 256) {
        float f = (float)s[j];
        acc += f * f;
    }
    for (int off = 32; off > 0; off >>= 1) acc += __shfl_xor(acc, off, 64);
    __shared__ float red[4];
    if (lane == 0) red[wave] = acc;
    __syncthreads();
    if (tid == 0) sq[row] = red[0] + red[1] + red[2] + red[3];
}

// W [K x N] fp32 -> Wt [N x K] bf16  (K=1024, N=768)
__global__ __launch_bounds__(256) void transpose_w(const float* __restrict__ W,
                                                   __bf16* __restrict__ Wt,
                                                   int K, int N) {
    __shared__ float tile[32][33];
    int bx = blockIdx.x * 32;  // along N
    int by = blockIdx.y * 32;  // along K
    int tx = threadIdx.x & 31, ty = threadIdx.x >> 5;  // ty 0..7
    for (int i = 0; i < 32; i += 8)
        tile[ty + i][tx] = W[(size_t)(by + ty + i) * N + bx + tx];
    __syncthreads();
    for (int i = 0; i < 32; i += 8)
        Wt[(size_t)(bx + ty + i) * K + by + tx] = (__bf16)tile[tx][ty + i];
}

// ---------------- small GEMM (m97 structure), used for e = x@W ----------------
// D = A[MxK] * Bt[NxK]^T, 128x128 tile, EPI==0: store bf16 raw.
template <int EPI>
__global__ __launch_bounds__(256) void gemm_bt(const __bf16* __restrict__ A,
                                               const __bf16* __restrict__ Bt,
                                               void* __restrict__ OutP,
                                               int M, int N, int K) {
    __shared__ __bf16 As[128 * 64];
    __shared__ __bf16 Bs[128 * 64];
    const int tid  = threadIdx.x;
    const int lane = tid & 63;
    const int wave = tid >> 6;

    int flat = blockIdx.x;
    int ntn = N / 128;
    int bm = (flat / ntn) * 128;
    int bn = (flat % ntn) * 128;

    floatx4 acc[4][4] = {};

    const int srow = lane >> 3;
    const int sc   = ((lane & 7) ^ srow) * 8;

    const int wm   = (wave & 1) * 64;
    const int wn   = (wave >> 1) * 64;
    const int frow = lane & 15;
    const int quad = lane >> 4;
    const int swz  = frow & 7;

    for (int k0 = 0; k0 < K; k0 += 64) {
        __syncthreads();
        #pragma unroll
        for (int i = 0; i < 4; ++i) {
            int row = wave * 32 + i * 8;
            const __bf16* ga = A  + (size_t)(bm + row + srow) * K + k0 + sc;
            gload_lds16(ga, &As[(size_t)row * 64]);
            const __bf16* gb = Bt + (size_t)(bn + row + srow) * K + k0 + sc;
            gload_lds16(gb, &Bs[(size_t)row * 64]);
        }
        asm volatile("s_waitcnt vmcnt(0)" ::: "memory");
        __syncthreads();

        #pragma unroll
        for (int kb = 0; kb < 2; ++kb) {
            bf16x8 af[4], bfr[4];
            #pragma unroll
            for (int mi = 0; mi < 4; ++mi)
                af[mi] = *(const bf16x8*)&As[(wm + mi * 16 + frow) * 64 +
                                             (((kb * 4 + quad) ^ swz) * 8)];
            #pragma unroll
            for (int ni = 0; ni < 4; ++ni)
                bfr[ni] = *(const bf16x8*)&Bs[(wn + ni * 16 + frow) * 64 +
                                              (((kb * 4 + quad) ^ swz) * 8)];
            #pragma unroll
            for (int mi = 0; mi < 4; ++mi)
                #pragma unroll
                for (int ni = 0; ni < 4; ++ni)
                    acc[mi][ni] = __builtin_amdgcn_mfma_f32_16x16x32_bf16(
                        bfr[ni], af[mi], acc[mi][ni], 0, 0, 0);
        }
    }

    const int mrow = lane & 15;
    const int nq   = (lane >> 4) * 4;
    __bf16* Out = (__bf16*)OutP;
    #pragma unroll
    for (int mi = 0; mi < 4; ++mi) {
        int row = bm + wm + mi * 16 + mrow;
        size_t rb = (size_t)row * N;
        #pragma unroll
        for (int ni = 0; ni < 4; ++ni) {
            int col = bn + wn + ni * 16 + nq;
            floatx4 a = acc[mi][ni];
            bf16x4 o;
            #pragma unroll
            for (int r = 0; r < 4; ++r) o[r] = (__bf16)a[r];
            *(bf16x4*)&Out[rb + col] = o;
        }
    }
}

// ---------------- big GEMM: 256x256 tile, 8-wave, 4-phase/K-tile counted-vmcnt pipeline ----------------
// D = A[MxK] * Bt[NxK]^T; out = 2*acc - esq[row] - csq[col] (fp32, nontemporal).
//
// Schedule (race-free invariants, audited r1):
//   stage stream during tile t:  P0: A.h0(t+1)->buf[t^1]   P1: A.h1(t+1)->buf[t^1]
//                                P2: B.h0(t+2)->buf[t]     P3: B.h1(t+2)->buf[t]
//   reads during tile t (from buf[t&1]): all 8 B-frags at P0; every wave executes
//   lgkmcnt(0) before its P0 MFMA, hence before P1's closing barrier -> B regions of
//   buf[t&1] are dead once any wave reaches P2 -> STAGE_B(t+2) into the same slot is
//   safe. A-frags: 2 row-pairs per phase; A regions of buf[t^1] are written a full
//   tile before their reads.
//   Boundary (after P3): s_waitcnt vmcnt(4) -- leaves ONLY the 4 newest loads
//   (B(t+2) halves) in flight; A(t+1) and B(t+1) are guaranteed landed, which is
//   exactly what tile t+1's P0 reads. Drains to vmcnt(0) for the last two tiles.
//   Raw s_barrier only (no __syncthreads in the loop -> no forced vmcnt(0) drain).
//   16 MFMA per phase wrapped in s_setprio(1/0)  [T5 pays only on phase-split schedules].
// LDS: 2 x (256x64) bf16 for A and B = 128 KiB -> 1 block/CU, 8 waves = 2/SIMD.
// Bank conflicts: chunk-XOR swizzle applied on the GLOBAL address side (linear LDS dest,
// as global_load_lds requires); ds_read_b128 then lands 2-way max (free).
template <int EPI>
__global__ __launch_bounds__(512, 2) void gemm256(const __bf16* __restrict__ A,
                                                  const __bf16* __restrict__ Bt,
                                                  void* __restrict__ OutP,
                                                  const float* __restrict__ esq,
                                                  const float* __restrict__ csq,
                                                  int M, int N, int K) {
    __shared__ __bf16 As[2][256 * 64];
    __shared__ __bf16 Bs[2][256 * 64];

    const int tid  = threadIdx.x;
    const int lane = tid & 63;
    const int wave = tid >> 6;      // 0..7
    const int wr   = wave >> 2;     // 0..1 : M half (128 rows)
    const int wc   = wave & 3;      // 0..3 : N quarter (64 cols)

    int bm, bn;
    {
        int flat = blockIdx.x;
        int ntn = N >> 8;                 // tiles along N
        if ((ntn & 7) == 0) {
            // XCD-stripe swizzle: XCD x owns ntn/8 consecutive bn tiles (B stripe ~3MB -> L2)
            int xcd = flat & 7, j = flat >> 3;
            int spx = ntn >> 3;
            bn = (xcd * spx + (j % spx)) << 8;
            bm = (j / spx) << 8;
        } else {
            bm = (flat / ntn) << 8;
            bn = (flat % ntn) << 8;
        }
    }

    const __bf16* Ablk = A  + (size_t)bm * K;
    const __bf16* Bblk = Bt + (size_t)bn * K;

    // staging lane geometry (pre-swizzled global source, linear LDS dest)
    const int srow = lane >> 3;                    // 0..7
    const int sc   = ((lane & 7) ^ srow) << 3;     // swizzled k-chunk (elements)
    // fragment-read lane geometry
    const int frow = lane & 15;
    const int quad = lane >> 4;
    const int swz  = frow & 7;

    floatx4 acc[8][4] = {};
    bf16x8 bfr[4][2];
    const int nt = K >> 6;

#define STAGE_A(BUF, T, H) { \
    const int r0_ = (H) * 128 + wave * 8; \
    const __bf16* g_ = Ablk + (size_t)(r0_ + srow) * K + ((T) << 6) + sc; \
    gload_lds16(g_, &As[BUF][r0_ * 64]); \
    gload_lds16(g_ + (size_t)64 * K, &As[BUF][(r0_ + 64) * 64]); \
}
#define STAGE_B(BUF, T, H) { \
    const int r0_ = (H) * 128 + wave * 8; \
    const __bf16* g_ = Bblk + (size_t)(r0_ + srow) * K + ((T) << 6) + sc; \
    gload_lds16(g_, &Bs[BUF][r0_ * 64]); \
    gload_lds16(g_ + (size_t)64 * K, &Bs[BUF][(r0_ + 64) * 64]); \
}

    // Prologue: B(0).h0, B(0).h1, A(0).h0, A(0).h1, B(1).h0, B(1).h1  (12 loads/thread).
    // vmcnt(4): tile0 fully landed; B(1) halves may remain in flight.
    STAGE_B(0, 0, 0)
    STAGE_B(0, 0, 1)
    STAGE_A(0, 0, 0)
    STAGE_A(0, 0, 1)
    if (nt > 1) {
        STAGE_B(1, 1, 0)
        STAGE_B(1, 1, 1)
        asm volatile("s_waitcnt vmcnt(4)" ::: "memory");
    } else {
        asm volatile("s_waitcnt vmcnt(0)" ::: "memory");
    }
    __builtin_amdgcn_s_barrier();

#define PHASE(MB, STAGE_STMT, DO_LDB) { \
    bf16x8 af[2][2]; \
    { \
        const __bf16* ap_ = Ac + (size_t)(wr * 128 + (MB) * 16 + frow) * 64; \
        af[0][0] = *(const bf16x8*)(ap_ + ((quad ^ swz) << 3)); \
        af[0][1] = *(const bf16x8*)(ap_ + (((4 + quad) ^ swz) << 3)); \
        af[1][0] = *(const bf16x8*)(ap_ + 16 * 64 + ((quad ^ swz) << 3)); \
        af[1][1] = *(const bf16x8*)(ap_ + 16 * 64 + (((4 + quad) ^ swz) << 3)); \
    } \
    if (DO_LDB) { \
        const __bf16* bp_ = Bc + (size_t)(wc * 64 + frow) * 64; \
        _Pragma("unroll") \
        for (int ni = 0; ni < 4; ++ni) { \
            bfr[ni][0] = *(const bf16x8*)(bp_ + ni * 16 * 64 + ((quad ^ swz) << 3)); \
            bfr[ni][1] = *(const bf16x8*)(bp_ + ni * 16 * 64 + (((4 + quad) ^ swz) << 3)); \
        } \
    } \
    STAGE_STMT; \
    __builtin_amdgcn_s_barrier(); \
    asm volatile("s_waitcnt lgkmcnt(0)" ::: "memory"); \
    __builtin_amdgcn_s_setprio(1); \
    _Pragma("unroll") \
    for (int ni = 0; ni < 4; ++ni) { \
        acc[(MB)][ni]     = __builtin_amdgcn_mfma_f32_16x16x32_bf16(bfr[ni][0], af[0][0], acc[(MB)][ni], 0, 0, 0); \
        acc[(MB)][ni]     = __builtin_amdgcn_mfma_f32_16x16x32_bf16(bfr[ni][1], af[0][1], acc[(MB)][ni], 0, 0, 0); \
        acc[(MB) + 1][ni] = __builtin_amdgcn_mfma_f32_16x16x32_bf16(bfr[ni][0], af[1][0], acc[(MB) + 1][ni], 0, 0, 0); \
        acc[(MB) + 1][ni] = __builtin_amdgcn_mfma_f32_16x16x32_bf16(bfr[ni][1], af[1][1], acc[(MB) + 1][ni], 0, 0, 0); \
    } \
    __builtin_amdgcn_s_setprio(0); \
}

    for (int t = 0; t < nt; ++t) {
        const int cur = t & 1;
        const __bf16* Ac = As[cur];
        const __bf16* Bc = Bs[cur];
        const bool pA = (t + 1 < nt);
        const bool pB = (t + 2 < nt);

        PHASE(0, if (pA) STAGE_A(cur ^ 1, t + 1, 0), 1)
        __builtin_amdgcn_s_barrier();
        PHASE(2, if (pA) STAGE_A(cur ^ 1, t + 1, 1), 0)
        __builtin_amdgcn_s_barrier();
        PHASE(4, if (pB) STAGE_B(cur, t + 2, 0), 0)
        __builtin_amdgcn_s_barrier();
        PHASE(6, if (pB) STAGE_B(cur, t + 2, 1), 0)
        // boundary: counted vmcnt (never 0 in steady state), single barrier
        if (pB) {
            asm volatile("s_waitcnt vmcnt(4)" ::: "memory");
        } else {
            asm volatile("s_waitcnt vmcnt(0)" ::: "memory");
        }
        __builtin_amdgcn_s_barrier();
    }

#undef PHASE
#undef STAGE_A
#undef STAGE_B

    // epilogue (swapped-operand layout): M-row = lane&15, N-col base = (lane>>4)*4
    const int mrow = lane & 15;
    const int nq   = (lane >> 4) << 2;
    if (EPI == 1) {
        float* Out = (float*)OutP;
        #pragma unroll
        for (int mi = 0; mi < 8; ++mi) {
            int row = bm + wr * 128 + mi * 16 + mrow;
            float es = esq[row];
            size_t rb = (size_t)row * N;
            #pragma unroll
            for (int ni = 0; ni < 4; ++ni) {
                int col = bn + wc * 64 + ni * 16 + nq;
                floatx4 cs = *(const floatx4*)&csq[col];
                floatx4 a = acc[mi][ni];
                floatx4 v;
                #pragma unroll
                for (int r = 0; r < 4; ++r)
                    v[r] = 2.0f * a[r] - es - cs[r];
                __builtin_nontemporal_store(v, (floatx4*)&Out[rb + col]);
            }
        }
    } else {
        __bf16* Out = (__bf16*)OutP;
        #pragma unroll
        for (int mi = 0; mi < 8; ++mi) {
            int row = bm + wr * 128 + mi * 16 + mrow;
            size_t rb = (size_t)row * N;
            #pragma unroll
            for (int ni = 0; ni < 4; ++ni) {
                int col = bn + wc * 64 + ni * 16 + nq;
                floatx4 a = acc[mi][ni];
                bf16x4 o;
                #pragma unroll
                for (int r = 0; r < 4; ++r) o[r] = (__bf16)a[r];
                *(bf16x4*)&Out[rb + col] = o;
            }
        }
    }
}

// ---------------- launch ----------------

extern "C" void kernel_launch(void* const* d_in, const int* in_sizes, int n_in,
                              void* d_out, int out_size, void* d_ws, size_t ws_size,
                              hipStream_t stream) {
    const float* x    = (const float*)d_in[0];  // [B, DIN]
    const float* W    = (const float*)d_in[1];  // [DIN, D]
    const float* cent = (const float*)d_in[2];  // [C, D]
    float* out = (float*)d_out;                 // [B, C]

    char* ws = (char*)d_ws;
    __bf16* xb  = (__bf16*)ws;  ws += (size_t)BB * DIN * 2;   // 16 MB
    __bf16* Wt  = (__bf16*)ws;  ws += (size_t)DD * DIN * 2;   // 1.5 MB
    __bf16* cb  = (__bf16*)ws;  ws += (size_t)CC * DD * 2;    // 24 MB
    float*  csq = (float*)ws;   ws += (size_t)CC * 4;
    __bf16* eb  = (__bf16*)ws;  ws += (size_t)BB * DD * 2;    // 12 MB
    float*  esq = (float*)ws;   ws += (size_t)BB * 4;

    // 1. x -> bf16 (8M elems, 4/thread)
    f2b_kernel<<<(BB * DIN) / (256 * 4), 256, 0, stream>>>((const float4*)x, (bf16x4*)xb);
    // 2. W [DIN x D] -> Wt [D x DIN] bf16
    transpose_w<<<dim3(DD / 32, DIN / 32), 256, 0, stream>>>(W, Wt, DIN, DD);
    // 3. centroids -> bf16 + c_sq (from rounded values)
    row_convert_sumsq_f32<<<CC, 256, 0, stream>>>(cent, cb, csq, DD);
    // 4. e = x @ W  (M=8192, N=768, K=1024), store bf16 (128^2 kernel: 384 blocks)
    gemm_bt<0><<<(BB / 128) * (DD / 128), 256, 0, stream>>>(xb, Wt, eb, BB, DD, DIN);
    // 5. e_sq from rounded e
    row_sumsq_bf16<<<BB, 256, 0, stream>>>(eb, esq, DD);
    // 6. out = 2 * e@centT - e_sq - c_sq  (M=8192, N=16384, K=768), 256^2 4-phase pipeline
    gemm256<1><<<(BB / 256) * (CC / 256), 512, 0, stream>>>(eb, cb, out, esq, csq,
                                                            BB, CC, DD);
}